// Round 3
// baseline (873.177 us; speedup 1.0000x reference)
//
#include <hip/hip_runtime.h>

// ---------------------------------------------------------------------------
// GeometricConstructorLegacy: fused DAG of small FC chains on MI355X.
//
// Dedup: up_p2==up_p1, up_c2==up_c1, up_l3==up_l2, d_l3==d_l2, d_c2==d_c1,
// d_p2==d_p1  -> 10 unique nodes. agg(msg,upd) folded into consumer layer-1.
// All deps are row-local -> ONE fused kernel, no barriers; each wave owns 32
// rows through the whole graph. Intermediates live in d_out slots (scratch
// then overwritten by the true outputs, always read-before-write per wave).
//
// GEMMs: f16 MFMA 16x16x32 (unambiguous v8f16 operand type; better mantissa
// than bf16), fp32 accum. N padded 132->144, hidden K->160.
// Weights prepacked (prep kernels) into per-lane fragment order:
//   frag[((kc*NT + nt)*64 + lane)*8 + j] = W[kc*32 + (lane>>4)*8 + j][nt*16 + (lane&15)]
// so B-loads are fully coalesced 16B/lane and identical across all blocks.
// ---------------------------------------------------------------------------

#define ACT_STRIDE 168   // f16 elems per LDS act row (336 B, conflict-benign)

typedef _Float16 f16_t;
typedef _Float16 f16x8 __attribute__((ext_vector_type(8)));
typedef float    f32x4 __attribute__((ext_vector_type(4)));

__device__ __forceinline__ f32x4 mfma16(f16x8 a, f16x8 b, f32x4 c) {
  return __builtin_amdgcn_mfma_f32_16x16x32_f16(a, b, c, 0, 0, 0);
}

// ---------------- prep 1: fold matrices U = (m * msg_w @ upd_w), bias vecs --
__global__ void prep1(const float* ppmw, const float* ppuw,
                      const float* ppmb, const float* ppub,
                      const float* mpmw, const float* mpuw,
                      const float* mpmb, const float* mpub,
                      float* ws) {
  int idx = blockIdx.x * 256 + threadIdx.x;
  if (idx < 16384) {                       // U_pp = 2 * pp_msg_w @ pp_upd_w
    int i = idx >> 7, j = idx & 127;
    float s = 0.f;
    for (int k = 0; k < 128; ++k) s += ppmw[i*128+k] * ppuw[k*128+j];
    ws[idx] = 2.f * s;
  } else if (idx < 32768) {                // U_mp = mp_msg_w @ mp_upd_w
    int t = idx - 16384; int i = t >> 7, j = t & 127;
    float s = 0.f;
    for (int k = 0; k < 128; ++k) s += mpmw[i*128+k] * mpuw[k*128+j];
    ws[idx] = s;
  } else if (idx < 33280) {                // vec_pp, vec_mp{1,2,4}
    int t = idx - 32768; int which = t >> 7, j = t & 127;
    float v;
    if (which == 0) {
      float s = 0.f; for (int k = 0; k < 128; ++k) s += ppmb[k] * ppuw[k*128+j];
      v = 2.f * s + ppub[j];
    } else {
      float s = 0.f; for (int k = 0; k < 128; ++k) s += mpmb[k] * mpuw[k*128+j];
      float m = (which == 1) ? 1.f : ((which == 2) ? 2.f : 4.f);
      v = m * s + mpub[j];
    }
    ws[idx] = v;
  }
}

// ---------------- prep 2: build all fragmented f16 weight blobs -------------
__global__ void prep2(const float* ppw0, const float* ppw1, const float* ppw2,
                      const float* lnw0, const float* lnw1, const float* lnw2, const float* lnw3,
                      const float* crw0, const float* crw1, const float* crw2, const float* crw3,
                      const float* mpw0, const float* mpw1, const float* mpw2,
                      float* ws) {
  constexpr int bs[20] = {0,73728,92160,115200,135680,154112,172544,190976,214016,
                          237056,257536,275968,299008,322048,342528,360960,379392,
                          397824,420864,441344};
  int idx = blockIdx.x * 256 + threadIdx.x;
  if (idx >= 441344) return;
  int b = 0;
#pragma unroll
  for (int i = 1; i < 19; ++i) if (idx >= bs[i]) b = i;
  int e = idx - bs[b];

  const float* S = nullptr; const float* U = nullptr;
  int mode = 0, rowOff = 0, rowOff2 = 0, ld = 132, Kr = 132, Nr = 132, NP = 144;
  float scale = 1.f;
  switch (b) {
    case 0:  S = ppw0; Kr = 512; break;                                  // pp L1 signal
    case 1:  S = ppw0; mode = 2; U = ws;          rowOff = 512; break;   // pp L1 folded c1 (x2 in U_pp)
    case 2:  S = ppw1; break;                                            // pp L2
    case 3:  S = ppw2; ld = 128; Nr = 128; NP = 128; break;              // pp L3
    case 4:  S = lnw0; mode = 1; rowOff2 = 128; Kr = 128; break;         // ln L1 a+b
    case 5:  S = lnw0; Kr = 128; break;                                  // ln L1 a
    case 6:  S = lnw0; rowOff = 128; Kr = 128; break;                    // ln L1 b
    case 7:  S = lnw1; break;
    case 8:  S = lnw2; break;
    case 9:  S = lnw3; ld = 128; Nr = 128; NP = 128; break;
    case 10: S = crw0; mode = 1; rowOff2 = 128; Kr = 128; break;         // cr L1 a+b
    case 11: S = crw1; break;
    case 12: S = crw2; break;
    case 13: S = crw3; ld = 128; Nr = 128; NP = 128; break;
    case 14: S = mpw0; Kr = 128; break;                                  // mp L1 sig-part
    case 15: S = mpw0; mode = 2; U = ws + 16384; rowOff = 128; break;            // mp fold x1
    case 16: S = mpw0; mode = 2; U = ws + 16384; rowOff = 128; scale = 2.f; break;// mp fold x2
    case 17: S = mpw1; break;
    case 18: S = mpw2; ld = 128; Nr = 128; NP = 128; break;
  }
  int NT = NP >> 4;
  int j = e & 7, lane = (e >> 3) & 63, ntkc = e >> 9;
  int nt = ntkc % NT, kc = ntkc / NT;
  int k = kc * 32 + (lane >> 4) * 8 + j;
  int n = nt * 16 + (lane & 15);
  float v = 0.f;
  if (mode == 2) {
    if (n < Nr) {
      float s = 0.f;
      const float* Up = U + k * 128;
      for (int q = 0; q < 128; ++q) s += Up[q] * S[(rowOff + q) * ld + n];
      v = scale * s;
    }
  } else {
    if (k < Kr && n < Nr) {
      v = S[(rowOff + k) * ld + n];
      if (mode == 1) v += S[(rowOff2 + k) * ld + n];
    }
  }
  f16_t* frag = (f16_t*)(ws + 36160);
  frag[idx] = (f16_t)v;
}

// ---------------- prep 3: padded / folded bias vectors ----------------------
__global__ void prep3(const float* ppb0, const float* ppb1, const float* ppb2,
                      const float* lnb0, const float* lnb1, const float* lnb2, const float* lnb3,
                      const float* crb0, const float* crb1, const float* crb2, const float* crb3,
                      const float* mpb0, const float* mpb1, const float* mpb2,
                      const float* ppw0, const float* mpw0,
                      float* ws) {
  int idx = blockIdx.x * 256 + threadIdx.x;
  if (idx >= 18 * 160) return;
  int b = idx / 160, n = idx % 160;
  float v = 0.f;
  switch (b) {
    case 0:  if (n < 132) v = ppb0[n]; break;
    case 1:  if (n < 132) { float s = ppb0[n]; const float* vp = ws + 32768;
               for (int q = 0; q < 128; ++q) s += vp[q] * ppw0[(512+q)*132 + n]; v = s; } break;
    case 2:  if (n < 132) v = ppb1[n]; break;
    case 3:  if (n < 128) v = ppb2[n]; break;
    case 4:  if (n < 132) v = lnb0[n]; break;
    case 5:  if (n < 132) v = lnb1[n]; break;
    case 6:  if (n < 132) v = lnb2[n]; break;
    case 7:  if (n < 128) v = lnb3[n]; break;
    case 8:  if (n < 132) v = crb0[n]; break;
    case 9:  if (n < 132) v = crb1[n]; break;
    case 10: if (n < 132) v = crb2[n]; break;
    case 11: if (n < 128) v = crb3[n]; break;
    case 12: if (n < 132) v = mpb0[n]; break;
    case 13: if (n < 132) { float s = mpb0[n]; const float* vp = ws + 32768 + 128;
               for (int q = 0; q < 128; ++q) s += vp[q] * mpw0[(128+q)*132 + n]; v = s; } break;
    case 14: if (n < 132) { float s = mpb0[n]; const float* vp = ws + 32768 + 256;
               for (int q = 0; q < 128; ++q) s += vp[q] * mpw0[(128+q)*132 + n]; v = s; } break;
    case 15: if (n < 132) { float s = mpb0[n]; const float* vp = ws + 32768 + 384;
               for (int q = 0; q < 128; ++q) s += vp[q] * mpw0[(128+q)*132 + n]; v = s; } break;
    case 16: if (n < 132) v = mpb1[n]; break;
    case 17: if (n < 128) v = mpb2[n]; break;
  }
  ws[33280 + idx] = v;
}

// ---------------- fused DAG kernel ------------------------------------------
struct NodeDesc {
  const float* srcA[4];
  const f16_t* srcW[4];
  int          srcKc[4];
  int nsrc, nmid;
  const float* b1;
  const f16_t* wm0; const float* bm0;
  const f16_t* wm1; const float* bm1;
  const f16_t* wl;  const float* bl;
  float* out0; float* out1;
};
struct AllArgs { NodeDesc nd[10]; };

__device__ __forceinline__ void epilogue_relu(f32x4 (&acc)[2][9], const float* bp,
                                              f16_t* act, int row0, int g, int r16) {
#pragma unroll
  for (int nt = 0; nt < 9; ++nt) {
    float bias = bp[nt * 16 + r16];
#pragma unroll
    for (int mt = 0; mt < 2; ++mt) {
      int rr = row0 + mt * 16 + g * 4;
      int cc = nt * 16 + r16;
#pragma unroll
      for (int r = 0; r < 4; ++r) {
        float v = fmaxf(acc[mt][nt][r] + bias, 0.f);
        act[(rr + r) * ACT_STRIDE + cc] = (f16_t)v;
      }
    }
  }
}

__global__ __launch_bounds__(256, 2) void fused_graph(AllArgs AA) {
  __shared__ f16_t act[128 * ACT_STRIDE];   // 42 KB; per-wave disjoint 32-row regions
  const int tid  = threadIdx.x;
  const int lane = tid & 63;
  const int wv   = tid >> 6;
  const int g    = lane >> 4;
  const int r16  = lane & 15;
  const int row0 = wv * 32;
  const int gRow0 = blockIdx.x * 128 + row0;

  for (int node = 0; node < 10; ++node) {
    const NodeDesc& A = AA.nd[node];
    f32x4 acc[2][9];
#pragma unroll
    for (int mt = 0; mt < 2; ++mt)
#pragma unroll
      for (int nt = 0; nt < 9; ++nt) acc[mt][nt] = f32x4{0.f, 0.f, 0.f, 0.f};

    // ---- layer 1: A-fragments straight from global fp32 sources ----
    for (int s = 0; s < A.nsrc; ++s) {
      const float* src = A.srcA[s];
      const f16x8* W   = (const f16x8*)A.srcW[s];
      const int nkc = A.srcKc[s];
      const int K   = nkc * 32;
      for (int kc = 0; kc < nkc; ++kc) {
        f16x8 a[2];
#pragma unroll
        for (int mt = 0; mt < 2; ++mt) {
          const float* p = src + (size_t)(gRow0 + mt * 16 + r16) * K + (kc * 32 + g * 8);
          float4 lo = *(const float4*)p;
          float4 hi = *(const float4*)(p + 4);
          f16x8 v;
          v[0] = (f16_t)lo.x; v[1] = (f16_t)lo.y; v[2] = (f16_t)lo.z; v[3] = (f16_t)lo.w;
          v[4] = (f16_t)hi.x; v[5] = (f16_t)hi.y; v[6] = (f16_t)hi.z; v[7] = (f16_t)hi.w;
          a[mt] = v;
        }
        const f16x8* Wk = W + (size_t)(kc * 9) * 64 + lane;
#pragma unroll
        for (int nt = 0; nt < 9; ++nt) {
          f16x8 bb = Wk[(size_t)nt * 64];
          acc[0][nt] = mfma16(a[0], bb, acc[0][nt]);
          acc[1][nt] = mfma16(a[1], bb, acc[1][nt]);
        }
      }
    }
    epilogue_relu(acc, A.b1, act, row0, g, r16);
    {  // zero pad cols [144,160) of this wave's 32 rows (K=160 reads)
      int zr = row0 + (lane >> 1);
      int zc = 144 + (lane & 1) * 8;
      *(int4*)&act[zr * ACT_STRIDE + zc] = make_int4(0, 0, 0, 0);
    }

    // ---- hidden layers (K=160 from LDS) ----
    for (int m = 0; m < A.nmid; ++m) {
      const f16x8* W = (const f16x8*)(m == 0 ? A.wm0 : A.wm1);
      const float* bm = (m == 0 ? A.bm0 : A.bm1);
#pragma unroll
      for (int mt = 0; mt < 2; ++mt)
#pragma unroll
        for (int nt = 0; nt < 9; ++nt) acc[mt][nt] = f32x4{0.f, 0.f, 0.f, 0.f};
#pragma unroll
      for (int kc = 0; kc < 5; ++kc) {
        f16x8 a[2];
#pragma unroll
        for (int mt = 0; mt < 2; ++mt)
          a[mt] = *(const f16x8*)&act[(row0 + mt * 16 + r16) * ACT_STRIDE + kc * 32 + g * 8];
        const f16x8* Wk = W + (size_t)(kc * 9) * 64 + lane;
#pragma unroll
        for (int nt = 0; nt < 9; ++nt) {
          f16x8 bb = Wk[(size_t)nt * 64];
          acc[0][nt] = mfma16(a[0], bb, acc[0][nt]);
          acc[1][nt] = mfma16(a[1], bb, acc[1][nt]);
        }
      }
      epilogue_relu(acc, bm, act, row0, g, r16);
    }

    // ---- final layer: K=160, N=128, fp32 store(s), no relu ----
#pragma unroll
    for (int mt = 0; mt < 2; ++mt)
#pragma unroll
      for (int nt = 0; nt < 8; ++nt) acc[mt][nt] = f32x4{0.f, 0.f, 0.f, 0.f};
    {
      const f16x8* W = (const f16x8*)A.wl;
#pragma unroll
      for (int kc = 0; kc < 5; ++kc) {
        f16x8 a[2];
#pragma unroll
        for (int mt = 0; mt < 2; ++mt)
          a[mt] = *(const f16x8*)&act[(row0 + mt * 16 + r16) * ACT_STRIDE + kc * 32 + g * 8];
        const f16x8* Wk = W + (size_t)(kc * 8) * 64 + lane;
#pragma unroll
        for (int nt = 0; nt < 8; ++nt) {
          f16x8 bb = Wk[(size_t)nt * 64];
          acc[0][nt] = mfma16(a[0], bb, acc[0][nt]);
          acc[1][nt] = mfma16(a[1], bb, acc[1][nt]);
        }
      }
      float* o0 = A.out0; float* o1 = A.out1;
#pragma unroll
      for (int nt = 0; nt < 8; ++nt) {
        float bias = A.bl[nt * 16 + r16];
#pragma unroll
        for (int mt = 0; mt < 2; ++mt) {
          size_t rr = (size_t)(gRow0 + mt * 16 + g * 4);
          int cc = nt * 16 + r16;
#pragma unroll
          for (int r = 0; r < 4; ++r) {
            float v = acc[mt][nt][r] + bias;
            o0[(rr + r) * 128 + cc] = v;
            if (o1) o1[(rr + r) * 128 + cc] = v;
          }
        }
      }
    }
    // RAW insurance: later nodes (same wave) re-read these rows from L2.
    asm volatile("s_waitcnt vmcnt(0)" ::: "memory");
  }
}

// ---------------- host ------------------------------------------------------
extern "C" void kernel_launch(void* const* d_in, const int* in_sizes, int n_in,
                              void* d_out, int out_size, void* d_ws, size_t ws_size,
                              hipStream_t stream) {
  (void)in_sizes; (void)n_in; (void)out_size; (void)ws_size;
  const float* in[37];
  for (int i = 0; i < 37; ++i) in[i] = (const float*)d_in[i];
  float* ws  = (float*)d_ws;
  float* out = (float*)d_out;

  static const int bs[19] = {0,73728,92160,115200,135680,154112,172544,190976,214016,
                             237056,257536,275968,299008,322048,342528,360960,379392,
                             397824,420864};
  f16_t* frag = (f16_t*)(ws + 36160);
  auto FB   = [&](int i) { return (const f16_t*)(frag + bs[i]); };
  auto BI   = [&](int i) { return (const float*)(ws + 33280 + i * 160); };
  auto SLOT = [&](int i) { return out + (size_t)i * 65536 * 128; };

  prep1<<<130, 256, 0, stream>>>(in[1], in[3], in[2], in[4],
                                 in[27], in[29], in[28], in[30], ws);
  prep2<<<1724, 256, 0, stream>>>(in[5], in[7], in[9],
                                  in[11], in[13], in[15], in[17],
                                  in[19], in[21], in[23], in[25],
                                  in[31], in[33], in[35], ws);
  prep3<<<12, 256, 0, stream>>>(in[6], in[8], in[10],
                                in[12], in[14], in[16], in[18],
                                in[20], in[22], in[24], in[26],
                                in[32], in[34], in[36],
                                in[5], in[31], ws);

  AllArgs AA{};
  { NodeDesc& n = AA.nd[0];                    // up_p1 -> slot0 (scratch)
    n.srcA[0] = in[0]; n.srcW[0] = FB(0); n.srcKc[0] = 16; n.nsrc = 1; n.nmid = 1;
    n.b1 = BI(0); n.wm0 = FB(2); n.bm0 = BI(2); n.wl = FB(3); n.bl = BI(3);
    n.out0 = SLOT(0); n.out1 = nullptr; }
  { NodeDesc& n = AA.nd[1];                    // up_l1 -> slot2 (scratch)
    n.srcA[0] = SLOT(0); n.srcW[0] = FB(4); n.srcKc[0] = 4; n.nsrc = 1; n.nmid = 2;
    n.b1 = BI(4); n.wm0 = FB(7); n.bm0 = BI(5); n.wm1 = FB(8); n.bm1 = BI(6);
    n.wl = FB(9); n.bl = BI(7); n.out0 = SLOT(2); n.out1 = nullptr; }
  { NodeDesc& n = AA.nd[2];                    // up_c1 -> slot3 (scratch)
    n.srcA[0] = SLOT(0); n.srcW[0] = FB(10); n.srcKc[0] = 4; n.nsrc = 1; n.nmid = 2;
    n.b1 = BI(8); n.wm0 = FB(11); n.bm0 = BI(9); n.wm1 = FB(12); n.bm1 = BI(10);
    n.wl = FB(13); n.bl = BI(11); n.out0 = SLOT(3); n.out1 = nullptr; }
  { NodeDesc& n = AA.nd[3];                    // up_p3 -> slot5 (scratch)
    n.srcA[0] = in[0];   n.srcW[0] = FB(0); n.srcKc[0] = 16;
    n.srcA[1] = SLOT(3); n.srcW[1] = FB(1); n.srcKc[1] = 4;
    n.nsrc = 2; n.nmid = 1;
    n.b1 = BI(1); n.wm0 = FB(2); n.bm0 = BI(2); n.wl = FB(3); n.bl = BI(3);
    n.out0 = SLOT(5); n.out1 = nullptr; }
  { NodeDesc& n = AA.nd[4];                    // up_l2 -> slot6 (scratch)
    n.srcA[0] = SLOT(0); n.srcW[0] = FB(5); n.srcKc[0] = 4;
    n.srcA[1] = SLOT(5); n.srcW[1] = FB(6); n.srcKc[1] = 4;
    n.nsrc = 2; n.nmid = 2;
    n.b1 = BI(4); n.wm0 = FB(7); n.bm0 = BI(5); n.wm1 = FB(8); n.bm1 = BI(6);
    n.wl = FB(9); n.bl = BI(7); n.out0 = SLOT(6); n.out1 = nullptr; }
  { NodeDesc& n = AA.nd[5];                    // d_l1 -> slot2
    n.srcA[0] = SLOT(2); n.srcW[0] = FB(14); n.srcKc[0] = 4; n.nsrc = 1; n.nmid = 1;
    n.b1 = BI(12); n.wm0 = FB(17); n.bm0 = BI(16); n.wl = FB(18); n.bl = BI(17);
    n.out0 = SLOT(2); n.out1 = nullptr; }
  { NodeDesc& n = AA.nd[6];                    // d_l2 -> slot6, slot7
    n.srcA[0] = SLOT(6); n.srcW[0] = FB(14); n.srcKc[0] = 4; n.nsrc = 1; n.nmid = 1;
    n.b1 = BI(12); n.wm0 = FB(17); n.bm0 = BI(16); n.wl = FB(18); n.bl = BI(17);
    n.out0 = SLOT(6); n.out1 = SLOT(7); }
  { NodeDesc& n = AA.nd[7];                    // d_p3 -> slot5
    n.srcA[0] = SLOT(5); n.srcW[0] = FB(14); n.srcKc[0] = 4;
    n.srcA[1] = SLOT(6); n.srcW[1] = FB(16); n.srcKc[1] = 4;   // 2x fold (d_l2+d_l3)
    n.nsrc = 2; n.nmid = 1;
    n.b1 = BI(14); n.wm0 = FB(17); n.bm0 = BI(16); n.wl = FB(18); n.bl = BI(17);
    n.out0 = SLOT(5); n.out1 = nullptr; }
  { NodeDesc& n = AA.nd[8];                    // d_c1 -> slot3, slot4
    n.srcA[0] = SLOT(3); n.srcW[0] = FB(14); n.srcKc[0] = 4;
    n.srcA[1] = SLOT(5); n.srcW[1] = FB(15); n.srcKc[1] = 4;   // 1x fold (d_p3)
    n.nsrc = 2; n.nmid = 1;
    n.b1 = BI(13); n.wm0 = FB(17); n.bm0 = BI(16); n.wl = FB(18); n.bl = BI(17);
    n.out0 = SLOT(3); n.out1 = SLOT(4); }
  { NodeDesc& n = AA.nd[9];                    // d_p1 -> slot0, slot1
    n.srcA[0] = SLOT(0); n.srcW[0] = FB(14); n.srcKc[0] = 4;   // up_p1
    n.srcA[1] = SLOT(2); n.srcW[1] = FB(15); n.srcKc[1] = 4;   // d_l1 x1
    n.srcA[2] = SLOT(3); n.srcW[2] = FB(16); n.srcKc[2] = 4;   // d_c1 x2
    n.srcA[3] = SLOT(6); n.srcW[3] = FB(15); n.srcKc[3] = 4;   // d_l2 x1
    n.nsrc = 4; n.nmid = 1;
    n.b1 = BI(15); n.wm0 = FB(17); n.bm0 = BI(16); n.wl = FB(18); n.bl = BI(17);
    n.out0 = SLOT(0); n.out1 = SLOT(1); }

  fused_graph<<<512, 256, 0, stream>>>(AA);
}